// Round 5
// baseline (106.879 us; speedup 1.0000x reference)
//
#include <hip/hip_runtime.h>
#include <math.h>

// Problem constants
#define NN   1024
#define PP   4
#define SS   12
#define MM   64
#define KK   16
#define LL   8
#define MKK  80          // M + K
#define NSYM 13          // S + 1

// Output layout (float element offsets in d_out)
#define OFF_PILOT  0
#define OFF_SIG    524288      // N*P*1*M*2
#define OFF_H      6815744     // + N*P*S*M*2
#define OFF_SCALAR 7340032     // + N*P*M*2

#define NOISE_PWR   1.5625e-4f             // PWR/(M*10^(0.1*SNR)) = 1/6400
#define NOISE_SCALE 8.8388347648318447e-3f // sqrt(NOISE_PWR/2)
#define INV_2SUM    0.1279105570f          // 1 / (2 * sum_{j<8} exp(-j/4))
#define W64_ANG    -0.09817477042468103f   // -2*pi/64

// ALGEBRA (verified r4): CP(16) >= L(8) => per-symbol circular conv;
// FFT(IFFT(X)) = X => info[s,k] = H64[k]*X[s,k] + NOISE_SCALE*FFT64(noise[s,K:])[k].
//
// PACK-2 FFT (this round): 2 complex per lane, one symbol per 32-lane half-wave.
// DIT input position p holds noise[bitrev6(p)]; for p=l5 and p=l5+32:
//   bitrev6(l5) = 2*bitrev5(l5), bitrev6(l5+32) = 2*bitrev5(l5)+1  -> one float4 load.
// Stages h=1..16 are cross-lane within the half; the h=32 stage is in-register
// between the lane's two slots. Output: E-slot = X[l5], O-slot = X[l5+32].

__device__ __forceinline__ float2 shflx(float2 v, int mask) {
    return make_float2(__shfl_xor(v.x, mask), __shfl_xor(v.y, mask));
}
__device__ __forceinline__ float2 cmul(float2 a, float2 b) {
    return make_float2(a.x*b.x - a.y*b.y, a.x*b.y + a.y*b.x);
}

__device__ __forceinline__ void fft64_pair(float2& vE, float2& vO,
                                           const float2* tw5, const float* sgn5,
                                           float2 w32) {
    #pragma unroll
    for (int s = 0; s < 5; ++s) {
        const float tx = tw5[s].x, ty = tw5[s].y, sg = sgn5[s];
        float2 aE = make_float2(vE.x*tx - vE.y*ty, vE.x*ty + vE.y*tx);
        float2 aO = make_float2(vO.x*tx - vO.y*ty, vO.x*ty + vO.y*tx);
        float2 oE = shflx(aE, 1 << s);
        float2 oO = shflx(aO, 1 << s);
        vE = make_float2(fmaf(sg, aE.x, oE.x), fmaf(sg, aE.y, oE.y));
        vO = make_float2(fmaf(sg, aO.x, oO.x), fmaf(sg, aO.y, oO.y));
    }
    // final stage (h=32) in-register: X[l5] = E + w^l5 * O ; X[l5+32] = E - w^l5 * O
    float2 aO = cmul(vO, w32);
    const float ex = vE.x, ey = vE.y;
    vE = make_float2(ex + aO.x, ey + aO.y);
    vO = make_float2(ex - aO.x, ey - aO.y);
}

__global__ __launch_bounds__(256) void ofdm_kernel(
    const float2* __restrict__ x,          // (NP, S, M)
    const float2* __restrict__ pilot_raw,  // (NP, M)
    const float2* __restrict__ cof_unit,   // (NP, L)
    const float2* __restrict__ noise_unit, // (NP, NSYM, MKK)
    float2* __restrict__ out_pilot,        // (NP, M)
    float2* __restrict__ out_sig,          // (NP, S, M)
    float2* __restrict__ out_H,            // (NP, M)
    float*  __restrict__ out_scalar)
{
    const int b    = blockIdx.x;
    const int tid  = threadIdx.x;
    const int wid  = tid >> 6;
    const int lane = tid & 63;
    const int l5   = lane & 31;
    const int half = lane >> 5;
    const int rb5  = (int)(__brev((unsigned)l5) >> 27);   // bitrev5(l5)

    const float2* xb  = x          + (size_t)b * (SS*MM);
    const float2* pb  = pilot_raw  + (size_t)b * MM;
    const float4* cb4 = (const float4*)(cof_unit + (size_t)b * LL);
    const float4* nb4 = (const float4*)(noise_unit + (size_t)b * (NSYM*MKK));

    // --- channel taps: 4 uniform float4 loads, scaled in registers ---
    float4 cq0 = cb4[0], cq1 = cb4[1], cq2 = cb4[2], cq3 = cb4[3];
    float2 cof[LL] = {
        {cq0.x, cq0.y}, {cq0.z, cq0.w}, {cq1.x, cq1.y}, {cq1.z, cq1.w},
        {cq2.x, cq2.y}, {cq2.z, cq2.w}, {cq3.x, cq3.y}, {cq3.z, cq3.w}};
    #pragma unroll
    for (int t = 0; t < LL; ++t) {
        float sc = sqrtf(__expf(-(float)t * 0.25f) * INV_2SUM);
        cof[t].x *= sc; cof[t].y *= sc;
    }

    // --- H64[lane] via Horner ---
    float sH, cH;
    __sincosf(W64_ANG * (float)lane, &sH, &cH);
    const float2 wH = make_float2(cH, sH);
    float2 H = cof[LL - 1];
    #pragma unroll
    for (int l = LL - 2; l >= 0; --l) {
        float2 Hw = cmul(H, wH);
        H = make_float2(Hw.x + cof[l].x, Hw.y + cof[l].y);
    }

    // --- per-lane stage twiddles (5 cross-lane stages, from l5) + final w32 ---
    float2 tw5[5];
    float  sgn5[5];
    #pragma unroll
    for (int s = 0; s < 5; ++s) {
        const int h = 1 << s;
        const bool up = (l5 & h) != 0;
        sgn5[s] = up ? -1.0f : 1.0f;
        float ang = -3.14159265358979323846f * (float)(l5 & (h - 1)) / (float)h;
        float sn, cs;
        __sincosf(ang, &sn, &cs);
        tw5[s] = up ? make_float2(cs, sn) : make_float2(1.0f, 0.0f);
    }
    float sW, cW;
    __sincosf(W64_ANG * (float)l5, &sW, &cW);
    const float2 w32 = make_float2(cW, sW);

    const size_t ob  = (size_t)b * MM;
    const size_t osb = (size_t)b * (SS * MM);

    auto do_pair = [&](int symA, int symB, bool storeB) {
        const int sym = half ? symB : symA;
        // noise: one aligned float4 = FFT-input positions l5 (E) and l5+32 (O)
        float4 nq = nb4[sym * (MKK/2) + (KK/2) + rb5];
        float2 vE = make_float2(NOISE_SCALE * nq.x, NOISE_SCALE * nq.y);
        float2 vO = make_float2(NOISE_SCALE * nq.z, NOISE_SCALE * nq.w);
        // H at the two output bins
        float2 HE = make_float2(__shfl(H.x, l5),      __shfl(H.y, l5));
        float2 HO = make_float2(__shfl(H.x, l5 | 32), __shfl(H.y, l5 | 32));
        float2 X1, X2;
        if (sym == 0) {   // pilot (only ever on half 0 of wave 0)
            float2 p1 = pb[l5], p2 = pb[l5 + 32];
            float ssq = p1.x*p1.x + p1.y*p1.y + p2.x*p2.x + p2.y*p2.y;
            #pragma unroll
            for (int off = 16; off > 0; off >>= 1)
                ssq += __shfl_xor(ssq, off);
            float alpha = sqrtf(64.0f / ssq);   // sqrt(PWR/2)/sqrt(mean(pilot_raw^2))
            X1 = make_float2(alpha * p1.x, alpha * p1.y);
            X2 = make_float2(alpha * p2.x, alpha * p2.y);
        } else {
            X1 = xb[(sym - 1) * MM + l5];
            X2 = xb[(sym - 1) * MM + l5 + 32];
        }
        fft64_pair(vE, vO, tw5, sgn5, w32);
        float2 r1 = cmul(HE, X1); r1.x += vE.x; r1.y += vE.y;
        float2 r2 = cmul(HO, X2); r2.x += vO.x; r2.y += vO.y;
        if (half == 0 || storeB) {
            if (sym == 0) {
                out_pilot[ob + l5]      = r1;
                out_pilot[ob + l5 + 32] = r2;
            } else {
                float2* o = out_sig + osb + (size_t)(sym - 1) * MM;
                o[l5]      = r1;
                o[l5 + 32] = r2;
            }
        }
    };

    if      (wid == 0) { do_pair(0, 1, true);  do_pair(8, 9, true);   }
    else if (wid == 1) { do_pair(2, 3, true);  do_pair(10, 11, true); }
    else if (wid == 2) { do_pair(4, 5, true);  do_pair(12, 12, false); }
    else               { do_pair(6, 7, true);  out_H[ob + lane] = H;  }

    if (b == 0 && tid == 0) out_scalar[0] = NOISE_PWR;
}

extern "C" void kernel_launch(void* const* d_in, const int* in_sizes, int n_in,
                              void* d_out, int out_size, void* d_ws, size_t ws_size,
                              hipStream_t stream) {
    const float2* x  = (const float2*)d_in[0];
    const float2* pr = (const float2*)d_in[1];
    const float2* cu = (const float2*)d_in[2];
    const float2* nu = (const float2*)d_in[3];

    float* out = (float*)d_out;
    float2* out_pilot = (float2*)(out + OFF_PILOT);
    float2* out_sig   = (float2*)(out + OFF_SIG);
    float2* out_H     = (float2*)(out + OFF_H);
    float*  out_sc    = out + OFF_SCALAR;

    ofdm_kernel<<<dim3(NN*PP), dim3(256), 0, stream>>>(
        x, pr, cu, nu, out_pilot, out_sig, out_H, out_sc);
}